// Round 5
// baseline (181.928 us; speedup 1.0000x reference)
//
#include <hip/hip_runtime.h>

// LIF net on MI355X.  Pipeline:
//  1. convert_W: Bt[kt][n][kk] bf16 linear (relu, K-pad to 832) + wrelu f32
//  2. gemm_hidden: bf16 MFMA, M padded 512/b; A dbuf in LDS (16KB), B frags
//     read per-lane from L2-resident Bt; lgkm-only barriers; transposed
//     epilogue -> Ih[b][h][512] bf16
//  3. scan_h: wave-per-row parallel LIF scan (shfl_up affine composition)
//  4. out_fused: per-b VALU dot (K=256,N=10) -> LDS -> segmented v_o scan
// ws: wrelu @0 (10KB) | Bt @16KB (416KB) | Ih @512KB (33.55MB)

typedef __attribute__((ext_vector_type(4))) float  floatx4;
typedef __attribute__((ext_vector_type(8))) short  shortx8;
typedef unsigned short u16;
typedef unsigned int   u32;

#define B_   128
#define NIN  784
#define NH   256
#define NO   10
#define T_   500
#define KT   13            // ceil(784/64), zero-padded

__device__ __forceinline__ u16 f2bf(float f) {
    union { float f; u32 u; } x; x.f = f;
    u32 r = x.u + 0x7FFFu + ((x.u >> 16) & 1u);   // RNE
    return (u16)(r >> 16);
}
__device__ __forceinline__ float bf2f(u16 u) {
    union { u32 u; float f; } x; x.u = ((u32)u) << 16; return x.f;
}
__device__ __forceinline__ float sigmoid5(float v) {
    return 1.0f / (1.0f + __expf(-5.0f * (v - 1.0f)));
}
__device__ __forceinline__ int swz8(int r) { return (r & 7) ^ ((r >> 3) & 7); }

// LDS-drain barrier that does NOT wait vmcnt (A reg-prefetch stays in flight)
__device__ __forceinline__ void bar() {
    asm volatile("s_waitcnt lgkmcnt(0)" ::: "memory");
    __builtin_amdgcn_s_barrier();
}

// ---------- Pre-pass: Bt (linear bf16 B, relu, padded) + wrelu ----------
__global__ void convert_W(const float* __restrict__ w_ih,
                          const float* __restrict__ w_ho,
                          u16* __restrict__ Bt, float* __restrict__ wrelu) {
    if (blockIdx.x == KT * 64) {        // last block: w_ho relu
        for (int i = threadIdx.x; i < NH * NO; i += 256)
            wrelu[i] = fmaxf(0.f, w_ho[i]);
        return;
    }
    const int k = blockIdx.x;           // 0..831
    const int n = threadIdx.x;          // 0..255
    float f = (k < NIN) ? fmaxf(0.f, w_ih[k * NH + n]) : 0.f;
    const int kt = k >> 6, kk = k & 63;
    Bt[(size_t)kt * (NH * 64) + n * 64 + kk] = f2bf(f);
}

// ---------- Phase A: hidden GEMM ----------
// Tile 64m x 256n, BK=64, 512 thr (8 waves 2x4), wave tile 32x64 (2x4 frags).
// M' = 128*512: m = b*512 + t (t>=500 -> zeros).  A: thread=(m8,k), 2x float4
// along t, transpose+cvt in regs, swizzled ds_write_b16, double-buffered,
// reg-prefetched 1 iter ahead.  B: per-lane 16B global loads from L2-resident
// Bt (no LDS, no prefetch needed: MFMA duty cycle is ~10%, waves cover it).
__global__ __launch_bounds__(512, 4) void gemm_hidden(
    const float* __restrict__ spikes,   // [128][784][500] f32
    const u16* __restrict__ Bt,         // [13][256][64] bf16
    u16* __restrict__ Ih)               // [128][256][512] bf16
{
    __shared__ u16 As[2][64 * 64];      // 8KB x2
    __shared__ u16 Cs[256 * 64];        // 32KB (epilogue transpose)

    const int tid  = threadIdx.x;
    const int row0 = blockIdx.x * 64;   // 1024 blocks
    const int bb   = row0 >> 9;
    const int t0   = row0 & 511;

    // A staging: thread covers m = m8..m8+7 (t = tt..tt+7) at k = kA
    const int m8 = (tid & 7) * 8;
    const int kA = tid >> 3;            // 0..63
    const int tt = t0 + m8;
    const bool tok = (tt < T_);
    const float* abase = spikes + (size_t)bb * (NIN * T_) + tt;

    const int lane = tid & 63, wid = tid >> 6;
    const int wm = wid >> 2, wn = wid & 3;
    const int lg = lane >> 4, lr = lane & 15;
    int aOff[2], bGOff[4];
#pragma unroll
    for (int i = 0; i < 2; ++i) {
        const int m = wm * 32 + i * 16 + lr;
        aOff[i] = m * 64 + ((lg * 8) ^ (swz8(m) << 3));
    }
#pragma unroll
    for (int i = 0; i < 4; ++i) {
        const int n = wn * 64 + i * 16 + lr;
        bGOff[i] = n * 64 + lg * 8;
    }

    floatx4 acc[2][4];
#pragma unroll
    for (int i = 0; i < 2; ++i)
#pragma unroll
        for (int j = 0; j < 4; ++j) acc[i][j] = (floatx4)0.f;

    // always-issue loads: clamp addr, select zero (no divergent skips)
#define LOADA(va, itv) {                                                       \
        const int kb = (itv) * 64 + kA;                                        \
        const bool ok = (kb < NIN) && tok;                                     \
        const float* p = ok ? (abase + (size_t)kb * T_) : spikes;              \
        floatx4 v0 = *(const floatx4*)p;                                       \
        floatx4 v1 = *(const floatx4*)(p + 4);                                 \
        va[0] = ok ? v0 : (floatx4)0.f;                                        \
        va[1] = ok ? v1 : (floatx4)0.f; }

#define WRITEA(buf, va) { _Pragma("unroll") for (int x = 0; x < 2; ++x)        \
        _Pragma("unroll") for (int q = 0; q < 4; ++q) {                        \
            const int j = 4 * x + q;                                           \
            As[buf][(m8 + j) * 64 + (kA ^ ((j ^ (tid & 7)) << 3))] =           \
                f2bf(va[x][q]); } }

#define MFMAIT(buf, bsrc) { _Pragma("unroll") for (int ks = 0; ks < 2; ++ks) { \
        shortx8 af[2], bfv[4];                                                 \
        _Pragma("unroll") for (int i = 0; i < 2; ++i)                          \
            af[i] = *(const shortx8*)&As[buf][aOff[i] ^ (ks * 32)];            \
        _Pragma("unroll") for (int i = 0; i < 4; ++i)                          \
            bfv[i] = *(const shortx8*)((bsrc) + bGOff[i] + ks * 32);           \
        _Pragma("unroll") for (int mi = 0; mi < 2; ++mi)                       \
        _Pragma("unroll") for (int ni = 0; ni < 4; ++ni)                       \
            acc[mi][ni] = __builtin_amdgcn_mfma_f32_16x16x32_bf16(             \
                af[mi], bfv[ni], acc[mi][ni], 0, 0, 0); } }

    floatx4 vaP[2], vaQ[2];

    // prologue
    LOADA(vaP, 0);
    WRITEA(0, vaP);                     // compiler waits vaP's vmcnt only
    LOADA(vaQ, 1);
    bar();

#define BODY(it, cur, nxt, vaW, vaL)                                            \
    WRITEA(nxt, vaW);                                                           \
    LOADA(vaL, (it) + 2);                                                       \
    MFMAIT(cur, Bt + (size_t)(it) * (NH * 64));                                 \
    bar();

    BODY(0, 0, 1, vaQ, vaP)   BODY(1, 1, 0, vaP, vaQ)
    BODY(2, 0, 1, vaQ, vaP)   BODY(3, 1, 0, vaP, vaQ)
    BODY(4, 0, 1, vaQ, vaP)   BODY(5, 1, 0, vaP, vaQ)
    BODY(6, 0, 1, vaQ, vaP)   BODY(7, 1, 0, vaP, vaQ)
    BODY(8, 0, 1, vaQ, vaP)   BODY(9, 1, 0, vaP, vaQ)
    BODY(10, 0, 1, vaQ, vaP)  BODY(11, 1, 0, vaP, vaQ)

    MFMAIT(0, Bt + (size_t)12 * (NH * 64));     // tail tile 12
    bar();

    // epilogue: transpose via Cs -> Ih[b][n][t0 + m]
#pragma unroll
    for (int mi = 0; mi < 2; ++mi)
#pragma unroll
        for (int r = 0; r < 4; ++r) {
            const int m = wm * 32 + mi * 16 + lg * 4 + r;
#pragma unroll
            for (int ni = 0; ni < 4; ++ni) {
                const int n = wn * 64 + ni * 16 + lr;
                Cs[n * 64 + (m ^ ((n & 7) << 3))] = f2bf(acc[mi][ni][r]);
            }
        }
    bar();
    {
        const int n  = tid >> 1, mh = tid & 1;
        u16* gdst = Ih + ((size_t)bb * 256 + n) * 512 + t0 + mh * 32;
#pragma unroll
        for (int j = 0; j < 4; ++j) {
            const uint4 v = *(const uint4*)&Cs[n * 64 + ((mh * 32 + 8 * j) ^ ((n & 7) << 3))];
            *(uint4*)(gdst + 8 * j) = v;
        }
    }
#undef LOADA
#undef WRITEA
#undef MFMAIT
#undef BODY
}

// ---------- Phase B: parallel hidden LIF scan (in place) ----------
// 32768 rows [b][h][512]; one wave per row; lane holds 8 t; affine
// composition scan across lanes (v' = a*v + b, a=0.9^8).
__global__ __launch_bounds__(512) void scan_h(u16* __restrict__ Ih) {
    const int lane = threadIdx.x & 63;
    const int row  = blockIdx.x * 8 + (threadIdx.x >> 6);
    u16* p = Ih + (size_t)row * 512 + lane * 8;
    shortx8 xv = *(const shortx8*)p;
    float I[8];
#pragma unroll
    for (int j = 0; j < 8; ++j) I[j] = bf2f((u16)xv[j]);
    float z = 0.f;
#pragma unroll
    for (int j = 0; j < 8; ++j) z += (I[j] - z) * 0.1f;
    float A = 0.43046721f, Bv = z;                 // 0.9^8
#pragma unroll
    for (int d = 1; d < 64; d <<= 1) {
        const float Au = __shfl_up(A, d);
        const float Bu = __shfl_up(Bv, d);
        if (lane >= d) { Bv = fmaf(A, Bu, Bv); A *= Au; }
    }
    float v = __shfl_up(Bv, 1);
    if (lane == 0) v = 0.f;
#pragma unroll
    for (int j = 0; j < 8; ++j) {
        v += (I[j] - v) * 0.1f;
        xv[j] = (short)f2bf(sigmoid5(v));
    }
    *(shortx8*)p = xv;
}

// ---------- Phase C+D: output dot + segmented v_o scan ----------
__global__ __launch_bounds__(512) void out_fused(
    const u16* __restrict__ s,          // [128][256][512] bf16
    const float* __restrict__ wr,       // [256][10] relu'd f32
    float* __restrict__ out)
{
    __shared__ float Io[T_ * NO];       // 20KB
    __shared__ float vend[25][NO], vstart[25][NO], psum[25][NO];
    const int b = blockIdx.x, tid = threadIdx.x;

    float acc[NO];
#pragma unroll
    for (int o = 0; o < NO; ++o) acc[o] = 0.f;
    const u16* sb = s + (size_t)b * NH * 512 + tid;
#pragma unroll 2
    for (int h = 0; h < NH; ++h) {
        const float sv = bf2f(sb[h * 512]);
#pragma unroll
        for (int o = 0; o < NO; ++o) acc[o] = fmaf(sv, wr[h * NO + o], acc[o]);
    }
    if (tid < T_) {
#pragma unroll
        for (int o = 0; o < NO; ++o) Io[tid * NO + o] = acc[o];
    }
    __syncthreads();

    const int seg = tid / NO, o = tid - seg * NO;
    if (tid < 250) {
        float v = 0.f;
#pragma unroll
        for (int j = 0; j < 20; ++j)
            v += (Io[(seg * 20 + j) * NO + o] - v) * 0.1f;
        vend[seg][o] = v;
    }
    __syncthreads();
    if (tid < NO) {
        float vs = 0.f;
#pragma unroll
        for (int sg = 0; sg < 25; ++sg) {
            vstart[sg][tid] = vs;
            vs = vend[sg][tid] + 0.12157665459f * vs;   // 0.9^20
        }
    }
    __syncthreads();
    if (tid < 250) {
        float v = vstart[seg][o], ps = 0.f;
#pragma unroll
        for (int j = 0; j < 20; ++j) {
            const int t = seg * 20 + j;
            v += (Io[t * NO + o] - v) * 0.1f;
            const float sv = sigmoid5(v);
            out[(size_t)b * (NO * T_) + (size_t)o * T_ + t] = sv;
            ps += sv;
        }
        psum[seg][o] = ps;
    }
    __syncthreads();
    if (tid < NO) {
        float tot = 0.f;
#pragma unroll
        for (int sg = 0; sg < 25; ++sg) tot += psum[sg][tid];
        out[(size_t)(B_ * NO) * T_ + b * NO + tid] = tot * (1.0f / T_);
    }
}

extern "C" void kernel_launch(void* const* d_in, const int* in_sizes, int n_in,
                              void* d_out, int out_size, void* d_ws, size_t ws_size,
                              hipStream_t stream) {
    (void)in_sizes; (void)n_in; (void)out_size; (void)ws_size;
    const float* spikes = (const float*)d_in[0];   // [128][784][500]
    const float* w_ih   = (const float*)d_in[1];   // [784][256]
    const float* w_ho   = (const float*)d_in[2];   // [256][10]
    float* out = (float*)d_out;

    float* wrelu = (float*)d_ws;                            // 10KB @0
    u16*   Bt    = (u16*)((char*)d_ws + 16384);             // 416KB
    u16*   Ih    = (u16*)((char*)d_ws + 524288);            // 33.55MB

    convert_W  <<<KT * 64 + 1, 256, 0, stream>>>(w_ih, w_ho, Bt, wrelu);
    gemm_hidden<<<1024, 512, 0, stream>>>(spikes, Bt, Ih);
    scan_h     <<<4096, 512, 0, stream>>>(Ih);
    out_fused  <<<B_, 512, 0, stream>>>(Ih, wrelu, out);
}

// Round 6
// 158.046 us; speedup vs baseline: 1.1511x; 1.1511x over previous
//
#include <hip/hip_runtime.h>

// LIF net on MI355X.  Pipeline:
//  1. convert_W: Bt[25][256][32] bf16 (relu, swizzled, K-pad 800) + wrelu f32
//  2. gemm_hidden: per block (64m x 256n): phase1 = stream A for FULL K into
//     resident LDS (104KB, one barrier total); phase2 = 25 k32-iters, B dbuf
//     16KB gload_lds, counted vmcnt(2); transposed epilogue -> Ih[b][h][512]
//  3. scan_h: wave-per-row parallel LIF scan (shfl_up affine composition)
//  4. out_fused: per-b VALU dot (K=256,N=10) -> LDS -> segmented v_o scan
// ws: wrelu @0 (10KB) | Bt @16KB (400KB) | Ih @512KB (33.55MB)

typedef __attribute__((ext_vector_type(4))) float  floatx4;
typedef __attribute__((ext_vector_type(8))) short  shortx8;
typedef unsigned short u16;
typedef unsigned int   u32;

#define B_   128
#define NIN  784
#define NH   256
#define NO   10
#define T_   500
#define KPAD 800           // 25 k-tiles of 32
#define AROW 832           // As row stride in u16 (1664B = 0 mod 128B)

__device__ __forceinline__ u16 f2bf(float f) {
    union { float f; u32 u; } x; x.f = f;
    u32 r = x.u + 0x7FFFu + ((x.u >> 16) & 1u);   // RNE
    return (u16)(r >> 16);
}
__device__ __forceinline__ float bf2f(u16 u) {
    union { u32 u; float f; } x; x.u = ((u32)u) << 16; return x.f;
}
__device__ __forceinline__ float sigmoid5(float v) {
    return 1.0f / (1.0f + __expf(-5.0f * (v - 1.0f)));
}

__device__ __forceinline__ void gload16(const u16* g, u16* l) {
    __builtin_amdgcn_global_load_lds(
        (const __attribute__((address_space(1))) unsigned int*)(const void*)g,
        (__attribute__((address_space(3))) unsigned int*)(void*)l, 16, 0, 0);
}

// ---------- Pre-pass: Bt[kt][n][slot] bf16 (relu, swizzled) + wrelu ----------
__global__ void convert_W(const float* __restrict__ w_ih,
                          const float* __restrict__ w_ho,
                          u16* __restrict__ Bt, float* __restrict__ wrelu) {
    if (blockIdx.x == KPAD) {           // last block: w_ho relu
        for (int i = threadIdx.x; i < NH * NO; i += 256)
            wrelu[i] = fmaxf(0.f, w_ho[i]);
        return;
    }
    const int k = blockIdx.x;           // 0..799
    const int n = threadIdx.x;          // 0..255
    const float f = (k < NIN) ? fmaxf(0.f, w_ih[k * NH + n]) : 0.f;
    const int kt = k >> 5, kk = k & 31;
    const int slot = ((((kk >> 3) ^ (n >> 1)) & 3) << 3) | (kk & 7);
    Bt[(size_t)kt * 8192 + n * 32 + slot] = f2bf(f);
}

// ---------- Phase A: hidden GEMM, A-resident-in-LDS structure ----------
// 512 thr (8 waves 2x4), wave tile 32m x 64n (2x4 frags, 32 acc).
// As[64][832] swizzled bf16 (104KB) holds the block's A for ALL K.
// Bs[2][256*32] (16KB x2) k32 double-buffer via gload_lds.
__global__ __launch_bounds__(512, 2) void gemm_hidden(
    const float* __restrict__ spikes,   // [128][784][500] f32
    const u16* __restrict__ Bt,         // [25][256][32] bf16 swizzled
    u16* __restrict__ Ih)               // [128][256][512] bf16
{
    __shared__ u16 As[64 * AROW];       // 104KB
    __shared__ u16 Bs[2][256 * 32];     // 16KB x2 (epilogue Cs reuses both)

    const int tid  = threadIdx.x;
    const int row0 = blockIdx.x * 64;   // 1024 blocks
    const int bb   = row0 >> 9;
    const int t0   = row0 & 511;

#define STAGEB(i) {                                                            \
        const u16* src = Bt + (size_t)(i) * 8192;                              \
        gload16(src + tid * 8,        &Bs[(i) & 1][tid * 8]);                  \
        gload16(src + 4096 + tid * 8, &Bs[(i) & 1][4096 + tid * 8]); }

    // issue B0,B1 first: their transfer rides under the whole A-phase
    STAGEB(0)
    STAGEB(1)

    // ---- phase 1: stream A (no barriers), convert+swizzle into As ----
    const int m4 = (tid & 15) * 4;      // m 0..63 in steps of 4
    const int kA = (tid >> 4) * 2;      // k-pair base 0..62
    const int tloc = t0 + m4;
    const bool tok = (tloc < T_);       // float4 never crosses b (500%4==0)
    const float* abase = spikes + (size_t)bb * (NIN * T_) + tloc;

#pragma unroll
    for (int p = 0; p < 13; ++p) {
        const int k0 = p * 64 + kA;
        if (k0 < KPAD) {
            const bool ok0 = tok && (k0 < NIN);
            const bool ok1 = tok && (k0 + 1 < NIN);
            const float* p0 = ok0 ? (abase + (size_t)k0 * T_) : abase;
            const float* p1 = ok1 ? (abase + (size_t)(k0 + 1) * T_) : abase;
            floatx4 v0 = *(const floatx4*)p0;
            floatx4 v1 = *(const floatx4*)p1;
            if (!ok0) v0 = (floatx4)0.f;
            if (!ok1) v1 = (floatx4)0.f;
#pragma unroll
            for (int j = 0; j < 4; ++j) {
                const int m = m4 + j;
                const int gr = (k0 >> 3) ^ (m & 7);
                const u32 pk = (u32)f2bf(v0[j]) | ((u32)f2bf(v1[j]) << 16);
                *(u32*)&As[m * AROW + (gr << 3) + (k0 & 7)] = pk;
            }
        }
    }
    __syncthreads();    // the ONE full drain: As complete, B0/B1 landed

    // ---- phase 2: K-loop, 25 iters ----
    const int lane = tid & 63, wid = tid >> 6;
    const int wm = wid >> 2, wn = wid & 3;
    const int lg = lane >> 4, lr = lane & 15;
    int mOff[2], mx[2], bOff[4];
#pragma unroll
    for (int mi = 0; mi < 2; ++mi) {
        const int m = wm * 32 + mi * 16 + lr;
        mOff[mi] = m * AROW;  mx[mi] = m & 7;
    }
#pragma unroll
    for (int ni = 0; ni < 4; ++ni) {
        const int n = wn * 64 + ni * 16 + lr;
        bOff[ni] = n * 32 + (((lg ^ (n >> 1)) & 3) << 3);
    }

    floatx4 acc[2][4];
#pragma unroll
    for (int i = 0; i < 2; ++i)
#pragma unroll
        for (int j = 0; j < 4; ++j) acc[i][j] = (floatx4)0.f;

#define MFMAI(i) {                                                             \
        const u16* bp = &Bs[(i) & 1][0];                                       \
        shortx8 af[2], bf[4];                                                  \
        _Pragma("unroll") for (int mi = 0; mi < 2; ++mi)                       \
            af[mi] = *(const shortx8*)&As[mOff[mi] +                           \
                        (((((i) * 4) + lg) ^ mx[mi]) << 3)];                   \
        _Pragma("unroll") for (int ni = 0; ni < 4; ++ni)                       \
            bf[ni] = *(const shortx8*)(bp + bOff[ni]);                         \
        _Pragma("unroll") for (int mi = 0; mi < 2; ++mi)                       \
        _Pragma("unroll") for (int ni = 0; ni < 4; ++ni)                       \
            acc[mi][ni] = __builtin_amdgcn_mfma_f32_16x16x32_bf16(             \
                af[mi], bf[ni], acc[mi][ni], 0, 0, 0); }

#define LGKMBAR { asm volatile("s_waitcnt lgkmcnt(0)" ::: "memory");           \
                  __builtin_amdgcn_s_barrier(); }

    // iter i (0..22): MFMA(i); bar; stage(i+2) into Bs[i&1]; wait B(i+1); bar
#define BODYM(i) MFMAI(i) LGKMBAR STAGEB((i) + 2)                              \
        asm volatile("s_waitcnt vmcnt(2)" ::: "memory");                       \
        __builtin_amdgcn_s_barrier();

    BODYM(0)  BODYM(1)  BODYM(2)  BODYM(3)  BODYM(4)  BODYM(5)
    BODYM(6)  BODYM(7)  BODYM(8)  BODYM(9)  BODYM(10) BODYM(11)
    BODYM(12) BODYM(13) BODYM(14) BODYM(15) BODYM(16) BODYM(17)
    BODYM(18) BODYM(19) BODYM(20) BODYM(21) BODYM(22)

    MFMAI(23) LGKMBAR                       // i=23: no stage
    asm volatile("s_waitcnt vmcnt(0)" ::: "memory");
    __builtin_amdgcn_s_barrier();
    MFMAI(24) LGKMBAR                       // i=24: Bs free after this

    // ---- epilogue: transpose via Cs (reuse Bs, 32KB) -> Ih[b][n][t0+m] ----
    u16* Cs = &Bs[0][0];                    // [256][64] u16
#pragma unroll
    for (int mi = 0; mi < 2; ++mi)
#pragma unroll
        for (int r = 0; r < 4; ++r) {
            const int m = wm * 32 + mi * 16 + lg * 4 + r;
#pragma unroll
            for (int ni = 0; ni < 4; ++ni) {
                const int n = wn * 64 + ni * 16 + lr;
                Cs[n * 64 + (m ^ ((n & 7) << 3))] = f2bf(acc[mi][ni][r]);
            }
        }
    LGKMBAR
    {
        const int n  = tid >> 1, mh = tid & 1;
        u16* gdst = Ih + ((size_t)bb * 256 + n) * 512 + t0 + mh * 32;
#pragma unroll
        for (int j = 0; j < 4; ++j) {
            const uint4 v = *(const uint4*)&Cs[n * 64 + ((mh * 32 + 8 * j) ^ ((n & 7) << 3))];
            *(uint4*)(gdst + 8 * j) = v;
        }
    }
#undef STAGEB
#undef MFMAI
#undef LGKMBAR
#undef BODYM
}

// ---------- Phase B: parallel hidden LIF scan (in place) ----------
// 32768 rows [b][h][512]; one wave per row; lane holds 8 t; affine
// composition scan across lanes (v' = a*v + b, a=0.9^8).
__global__ __launch_bounds__(512) void scan_h(u16* __restrict__ Ih) {
    const int lane = threadIdx.x & 63;
    const int row  = blockIdx.x * 8 + (threadIdx.x >> 6);
    u16* p = Ih + (size_t)row * 512 + lane * 8;
    shortx8 xv = *(const shortx8*)p;
    float I[8];
#pragma unroll
    for (int j = 0; j < 8; ++j) I[j] = bf2f((u16)xv[j]);
    float z = 0.f;
#pragma unroll
    for (int j = 0; j < 8; ++j) z += (I[j] - z) * 0.1f;
    float A = 0.43046721f, Bv = z;                 // 0.9^8
#pragma unroll
    for (int d = 1; d < 64; d <<= 1) {
        const float Au = __shfl_up(A, d);
        const float Bu = __shfl_up(Bv, d);
        if (lane >= d) { Bv = fmaf(A, Bu, Bv); A *= Au; }
    }
    float v = __shfl_up(Bv, 1);
    if (lane == 0) v = 0.f;
#pragma unroll
    for (int j = 0; j < 8; ++j) {
        v += (I[j] - v) * 0.1f;
        xv[j] = (short)f2bf(sigmoid5(v));
    }
    *(shortx8*)p = xv;
}

// ---------- Phase C+D: output dot + segmented v_o scan ----------
__global__ __launch_bounds__(512) void out_fused(
    const u16* __restrict__ s,          // [128][256][512] bf16
    const float* __restrict__ wr,       // [256][10] relu'd f32
    float* __restrict__ out)
{
    __shared__ float Io[T_ * NO];       // 20KB
    __shared__ float vend[25][NO], vstart[25][NO], psum[25][NO];
    const int b = blockIdx.x, tid = threadIdx.x;

    float acc[NO];
#pragma unroll
    for (int o = 0; o < NO; ++o) acc[o] = 0.f;
    const u16* sb = s + (size_t)b * NH * 512 + tid;
#pragma unroll 2
    for (int h = 0; h < NH; ++h) {
        const float sv = bf2f(sb[h * 512]);
#pragma unroll
        for (int o = 0; o < NO; ++o) acc[o] = fmaf(sv, wr[h * NO + o], acc[o]);
    }
    if (tid < T_) {
#pragma unroll
        for (int o = 0; o < NO; ++o) Io[tid * NO + o] = acc[o];
    }
    __syncthreads();

    const int seg = tid / NO, o = tid - seg * NO;
    if (tid < 250) {
        float v = 0.f;
#pragma unroll
        for (int j = 0; j < 20; ++j)
            v += (Io[(seg * 20 + j) * NO + o] - v) * 0.1f;
        vend[seg][o] = v;
    }
    __syncthreads();
    if (tid < NO) {
        float vs = 0.f;
#pragma unroll
        for (int sg = 0; sg < 25; ++sg) {
            vstart[sg][tid] = vs;
            vs = vend[sg][tid] + 0.12157665459f * vs;   // 0.9^20
        }
    }
    __syncthreads();
    if (tid < 250) {
        float v = vstart[seg][o], ps = 0.f;
#pragma unroll
        for (int j = 0; j < 20; ++j) {
            const int t = seg * 20 + j;
            v += (Io[t * NO + o] - v) * 0.1f;
            const float sv = sigmoid5(v);
            out[(size_t)b * (NO * T_) + (size_t)o * T_ + t] = sv;
            ps += sv;
        }
        psum[seg][o] = ps;
    }
    __syncthreads();
    if (tid < NO) {
        float tot = 0.f;
#pragma unroll
        for (int sg = 0; sg < 25; ++sg) tot += psum[sg][tid];
        out[(size_t)(B_ * NO) * T_ + b * NO + tid] = tot * (1.0f / T_);
    }
}

extern "C" void kernel_launch(void* const* d_in, const int* in_sizes, int n_in,
                              void* d_out, int out_size, void* d_ws, size_t ws_size,
                              hipStream_t stream) {
    (void)in_sizes; (void)n_in; (void)out_size; (void)ws_size;
    const float* spikes = (const float*)d_in[0];   // [128][784][500]
    const float* w_ih   = (const float*)d_in[1];   // [784][256]
    const float* w_ho   = (const float*)d_in[2];   // [256][10]
    float* out = (float*)d_out;

    float* wrelu = (float*)d_ws;                            // 10KB @0
    u16*   Bt    = (u16*)((char*)d_ws + 16384);             // 400KB
    u16*   Ih    = (u16*)((char*)d_ws + 524288);            // 33.55MB

    convert_W  <<<KPAD + 1, 256, 0, stream>>>(w_ih, w_ho, Bt, wrelu);
    gemm_hidden<<<1024, 512, 0, stream>>>(spikes, Bt, Ih);
    scan_h     <<<4096, 512, 0, stream>>>(Ih);
    out_fused  <<<B_, 512, 0, stream>>>(Ih, wrelu, out);
}